// Round 1
// 842.090 us; speedup vs baseline: 1.1327x; 1.1327x over previous
//
#include <hip/hip_runtime.h>
#include <hip/hip_fp16.h>

typedef _Float16 f16x8 __attribute__((ext_vector_type(8)));
typedef _Float16 f16x2 __attribute__((ext_vector_type(2)));
typedef float f32x4 __attribute__((ext_vector_type(4)));
typedef short s16x8 __attribute__((ext_vector_type(8)));

typedef __attribute__((address_space(1))) void gvoid;
typedef __attribute__((address_space(3))) void lvoid;

#define GLD_LDS16(g, l) __builtin_amdgcn_global_load_lds((gvoid*)(g), (lvoid*)(l), 16, 0, 0)
#define BAR() __builtin_amdgcn_s_barrier()

// ---- fp32 -> fp16 downcast, 8 elems/thread, 16B stores ----
__global__ __launch_bounds__(256) void cvt_f32_f16(
    const float* __restrict__ src, _Float16* __restrict__ dst, int n8)
{
    const int i = blockIdx.x * 256 + threadIdx.x;
    if (i >= n8) return;
    const float4* s = (const float4*)src;
    const float4 a = s[2 * i], b = s[2 * i + 1];
    f16x8 o;
    o[0] = (_Float16)a.x; o[1] = (_Float16)a.y; o[2] = (_Float16)a.z; o[3] = (_Float16)a.w;
    o[4] = (_Float16)b.x; o[5] = (_Float16)b.y; o[6] = (_Float16)b.z; o[7] = (_Float16)b.w;
    *(f16x8*)(dst + (size_t)i * 8) = o;
}

// ============================================================================
// C[M,N] = A[M,K] @ B[N,K]^T + bias[N]; f16 in, fp32 acc, OutT out.
// 256x256 tile, BK=64, 512 threads (8 waves, 2M x 4N), 16x16x32 f16 MFMA.
// 8-phase schedule (guide m201 template): per K-tile 4 phases, each
//   { ds_read subtile ; stage 1 half-tile (2x global_load_lds) ;
//     s_barrier ; setprio(1) 16xMFMA setprio(0) ; s_barrier }
// Raw s_barrier (NOT __syncthreads) so global_load_lds stay in flight across
// barriers; counted s_waitcnt vmcnt(2) ONCE per K-tile.
//
// LDS 128 KiB: smem[d][mat][256][64] f16, rows as 8 chunks of 8 f16,
// phys chunk = logical ^ (row & 7)  (source pre-swizzled, read swizzled;
// fragment ds_read_b128 is then 2-way max = free).
//
// Stage stream ledger (steady state, tile t reads buf d = t&1):
//   t.ph1: HT(t+1, A1)->d^1   (buf d^1 A1 last read tile t-1 ph3, barriered)
//   t.ph2: HT(t+1, B0)->d^1   (last read tile t-1 ph1)
//   t.ph3: HT(t+1, B1)->d^1   (last read tile t-1 ph2/3)
//   t.ph4: HT(t+2, A0)->d     (buf d A0 last read THIS tile ph1, barriered)
//   [HT(t+1, A0) was issued at t-1.ph4]
// End-of-tile: vmcnt(2) leaves only HT(t+2,A0)'s 2 loads outstanding ->
// all of tile t+1 landed; barrier; proceed.
// ds_reads/wave/tile = 24 (minimal): ph1 12 (A0+B0), ph2 4 (B1), ph3 8 (A1),
// ph4 0 (fb0,fb1 register-held).
// grid: 1-D, XCD-bijective swizzle (grid % 8 == 0 for both call sites).
// ============================================================================
template <typename OutT>
__global__ __launch_bounds__(512, 1) void gemm_bt_bias(
    const _Float16* __restrict__ A, int lda,
    const _Float16* __restrict__ B,        // ldb == K
    const float* __restrict__ bias,
    OutT* __restrict__ C, int ldc,
    int K, int nbx)
{
    __shared__ alignas(16) _Float16 smem[65536];   // 128 KiB

    const int tid = threadIdx.x;
    const int lane = tid & 63, wv = tid >> 6;
    const int nwg = gridDim.x;
    int bid = blockIdx.x;
    if ((nwg & 7) == 0) bid = (bid & 7) * (nwg >> 3) + (bid >> 3);
    const int m0 = (bid / nbx) * 256, n0 = (bid % nbx) * 256;
    const int wm = wv >> 2, wn = wv & 3;            // wave -> 128x64 sub-tile
    const int l15 = lane & 15, q4 = lane >> 4, l7 = lane & 7;
    const int nk = K >> 6;

    // staging sources: slot s = e*512 + tid; row = s>>3, phys chunk = s&7,
    // fetched logical chunk = (s&7) ^ (row&7). e=0: rows 0..63, e=1: 64..127.
    const int rl = tid >> 3;
    const int cl = (tid & 7) ^ (rl & 7);
    const _Float16* gp00 = A + (size_t)(m0 + rl) * lda + cl * 8;
    const _Float16* gp01 = A + (size_t)(m0 + 64 + rl) * lda + cl * 8;
    const _Float16* gp10 = A + (size_t)(m0 + 128 + rl) * lda + cl * 8;
    const _Float16* gp11 = A + (size_t)(m0 + 192 + rl) * lda + cl * 8;
    const _Float16* gp20 = B + (size_t)(n0 + rl) * (size_t)K + cl * 8;
    const _Float16* gp21 = B + (size_t)(n0 + 64 + rl) * (size_t)K + cl * 8;
    const _Float16* gp30 = B + (size_t)(n0 + 128 + rl) * (size_t)K + cl * 8;
    const _Float16* gp31 = B + (size_t)(n0 + 192 + rl) * (size_t)K + cl * 8;

    f32x4 acc[8][4];
#pragma unroll
    for (int i = 0; i < 8; ++i)
#pragma unroll
        for (int j = 0; j < 4; ++j)
            acc[i][j] = (f32x4){0.f, 0.f, 0.f, 0.f};

    f16x8 fa[4][2], fb0[2][2], fb1[2][2];

// stage half-tile J of K-tile tile_ (J: 0=A rows[0,128) 1=A[128,256)
// 2=B[0,128) 3=B[128,256)); 2 x global_load_lds per thread, linear LDS dest.
#define STAGE(J, tile_) do {                                                  \
    const int dd_ = (tile_) & 1;                                              \
    _Float16* lb_ = &smem[dd_ * 32768 + ((J) >> 1) * 16384 +                  \
                          ((J) & 1) * 8192 + wv * 512];                       \
    const size_t ko_ = (size_t)(tile_) * 64;                                  \
    GLD_LDS16(gp##J##0 + ko_, lb_);                                           \
    GLD_LDS16(gp##J##1 + ko_, lb_ + 4096);                                    \
} while (0)

// fragment reads: A row = wm*128 + mq*64 + fi*16 + l15, k-chunk ks*4+q4,
// phys chunk XOR (row&7) = XOR l7 (row offsets are all multiples of 16).
#define RD_A(d_, mq_) do {                                                    \
    const _Float16* ba_ = &smem[(d_) * 32768];                                \
    _Pragma("unroll")                                                         \
    for (int fi = 0; fi < 4; ++fi) {                                          \
        const int r_ = wm * 128 + (mq_) * 64 + fi * 16 + l15;                 \
        fa[fi][0] = *(const f16x8*)(ba_ + r_ * 64 + ((q4 ^ l7) * 8));         \
        fa[fi][1] = *(const f16x8*)(ba_ + r_ * 64 + (((4 + q4) ^ l7) * 8));   \
    }                                                                         \
} while (0)

#define RD_B(d_, nq_, fbv) do {                                               \
    const _Float16* bb_ = &smem[(d_) * 32768 + 16384];                        \
    _Pragma("unroll")                                                         \
    for (int fj = 0; fj < 2; ++fj) {                                          \
        const int r_ = wn * 64 + (nq_) * 32 + fj * 16 + l15;                  \
        fbv[fj][0] = *(const f16x8*)(bb_ + r_ * 64 + ((q4 ^ l7) * 8));        \
        fbv[fj][1] = *(const f16x8*)(bb_ + r_ * 64 + (((4 + q4) ^ l7) * 8));  \
    }                                                                         \
} while (0)

// one C-quadrant x K=64: 16 MFMA, setprio-wrapped (T5)
#define MM(mq_, nq_, fbv) do {                                                \
    __builtin_amdgcn_s_setprio(1);                                            \
    _Pragma("unroll")                                                         \
    for (int ks = 0; ks < 2; ++ks)                                            \
    _Pragma("unroll")                                                         \
    for (int fi = 0; fi < 4; ++fi)                                            \
    _Pragma("unroll")                                                         \
    for (int fj = 0; fj < 2; ++fj)                                            \
        acc[(mq_) * 4 + fi][(nq_) * 2 + fj] =                                 \
            __builtin_amdgcn_mfma_f32_16x16x32_f16(                           \
                fa[fi][ks], fbv[fj][ks],                                      \
                acc[(mq_) * 4 + fi][(nq_) * 2 + fj], 0, 0, 0);                \
    __builtin_amdgcn_s_setprio(0);                                            \
} while (0)

#define GTILE(d_, S1, S2, S3, S4, VMN) do {                                   \
    RD_A(d_, 0); RD_B(d_, 0, fb0);                                           \
    S1;                                                                       \
    BAR(); MM(0, 0, fb0); BAR();                                              \
    RD_B(d_, 1, fb1);                                                         \
    S2;                                                                       \
    BAR(); MM(0, 1, fb1); BAR();                                              \
    RD_A(d_, 1);                                                              \
    S3;                                                                       \
    BAR(); MM(1, 1, fb1); BAR();                                              \
    S4;                                                                       \
    BAR(); MM(1, 0, fb0);                                                     \
    asm volatile("s_waitcnt vmcnt(" #VMN ")" ::: "memory");                   \
    BAR();                                                                    \
} while (0)

    // prologue: tile0 fully + HT(1,A0); wait tile0 (10 issued, newest 2 ok)
    STAGE(0, 0); STAGE(1, 0); STAGE(2, 0); STAGE(3, 0);
    if (nk > 1) {
        STAGE(0, 1);
        asm volatile("s_waitcnt vmcnt(2)" ::: "memory");
    } else {
        asm volatile("s_waitcnt vmcnt(0)" ::: "memory");
    }
    BAR();

    for (int kt = 0; kt < nk - 2; ++kt) {
        const int d = kt & 1;
        GTILE(d, STAGE(1, kt + 1), STAGE(2, kt + 1), STAGE(3, kt + 1),
              STAGE(0, kt + 2), 2);
    }
    if (nk >= 2) {
        // tile nk-2: stage rest of tile nk-1, no tile nk -> drain fully
        GTILE((nk - 2) & 1, STAGE(1, nk - 1), STAGE(2, nk - 1),
              STAGE(3, nk - 1), (void)0, 0);
    }
    {   // last tile: no staging, no barriers needed
        const int d = (nk - 1) & 1;
        RD_A(d, 0); RD_B(d, 0, fb0);
        MM(0, 0, fb0);
        RD_B(d, 1, fb1);
        MM(0, 1, fb1);
        RD_A(d, 1);
        MM(1, 1, fb1);
        MM(1, 0, fb0);
    }

#undef GTILE
#undef MM
#undef RD_B
#undef RD_A
#undef STAGE

    // epilogue: 16x16 C/D layout col=lane&15, row=(lane>>4)*4+reg
#pragma unroll
    for (int nj = 0; nj < 4; ++nj) {
        const int col = n0 + wn * 64 + nj * 16 + l15;
        const float bs = bias[col];
#pragma unroll
        for (int mi = 0; mi < 8; ++mi) {
            const int row = m0 + wm * 128 + mi * 16 + q4 * 4;
#pragma unroll
            for (int i = 0; i < 4; ++i)
                C[(size_t)(row + i) * ldc + col] = (OutT)(acc[mi][nj][i] + bs);
        }
    }
}

// Fused attention per (b,h): scores = QK^T/sqrt(2048), causal (keep q>=k),
// softmax over the QUERY axis per key-column, O = P V. O overwrites the
// Q region of qkv. V kept ROW-MAJOR stride 134 (odd dwords -> full bank
// spread); PV B-frags built from 8 scalar ds_read_u16 at 2-way (free).
// LDS 53 KB -> 3 blocks/CU. grid = 4096 blocks.
__global__ __launch_bounds__(256) void attn_fused(_Float16* __restrict__ qkv)
{
    constexpr float SCALE = 0.022097086912079608f; // 1/sqrt(2048)
    __shared__ alignas(16) char smem[51968];
    __shared__ float sRed[256];
    _Float16* sQ = (_Float16*)smem;              // [64][136]
    _Float16* sK = (_Float16*)(smem + 17408);    // [64][136]
    _Float16* sV = (_Float16*)(smem + 34816);    // [64][134] row-major
    float* sSt = (float*)smem;                   // [64][65] scores [key][q] (reuses sQ)
    _Float16* sP = (_Float16*)(smem + 17408);    // [64][72]  P[q][k] (reuses sK)

    const int t = threadIdx.x;
    const int bh = blockIdx.x;
    const int b = bh >> 4, h = bh & 15;
    const int ld = 6144;
    const _Float16* Qg = qkv + (size_t)b * 64 * ld + h * 128;
    const _Float16* Kg = Qg + 2048;
    const _Float16* Vg = Qg + 4096;
    _Float16* Og = qkv + (size_t)b * 64 * ld + h * 128;

    // ---- load Q,K padded row-major; V row-major stride 134 ----
    for (int i = t; i < 1024; i += 256) {
        const int r = i >> 4, c = (i & 15) * 8;
        *(s16x8*)(sQ + r * 136 + c) = *(const s16x8*)(Qg + (size_t)r * ld + c);
        *(s16x8*)(sK + r * 136 + c) = *(const s16x8*)(Kg + (size_t)r * ld + c);
        const f16x8 vv = *(const f16x8*)(Vg + (size_t)r * ld + c);
#pragma unroll
        for (int p = 0; p < 4; ++p) {
            f16x2 w2; w2[0] = vv[2 * p]; w2[1] = vv[2 * p + 1];
            *(f16x2*)(sV + r * 134 + c + 2 * p) = w2;
        }
    }
    __syncthreads();

    const int lane = t & 63, w = t >> 6;
    const int l15 = lane & 15, q4 = lane >> 4;
    const f32x4 fz = {0.f, 0.f, 0.f, 0.f};

    // ---- scores: wave w computes q-rows [w*16, w*16+16) x all 64 keys ----
    f32x4 sc[4];
#pragma unroll
    for (int nt = 0; nt < 4; ++nt) sc[nt] = fz;
#pragma unroll
    for (int kk = 0; kk < 128; kk += 32) {
        const f16x8 aq = *(const f16x8*)(sQ + (w * 16 + l15) * 136 + kk + q4 * 8);
#pragma unroll
        for (int nt = 0; nt < 4; ++nt) {
            const f16x8 bk = *(const f16x8*)(sK + (nt * 16 + l15) * 136 + kk + q4 * 8);
            sc[nt] = __builtin_amdgcn_mfma_f32_16x16x32_f16(aq, bk, sc[nt], 0, 0, 0);
        }
    }
    __syncthreads();  // done reading sQ/sK before overwrite

    // write scores transposed: sSt[key][query]
#pragma unroll
    for (int nt = 0; nt < 4; ++nt)
#pragma unroll
        for (int i = 0; i < 4; ++i)
            sSt[(nt * 16 + l15) * 65 + (w * 16 + q4 * 4 + i)] = sc[nt][i] * SCALE;
    __syncthreads();

    // ---- column softmax over query axis (4 threads per key column) ----
    {
        const int k = t >> 2, j = t & 3;
        const int qlo = max(k, j * 16), qhi = min(64, j * 16 + 16);
        float mx = -3.0e38f;
        for (int q = qlo; q < qhi; ++q) mx = fmaxf(mx, sSt[k * 65 + q]);
        sRed[t] = mx;
        __syncthreads();
        mx = fmaxf(fmaxf(sRed[k * 4 + 0], sRed[k * 4 + 1]),
                   fmaxf(sRed[k * 4 + 2], sRed[k * 4 + 3]));
        float sum = 0.f;
        for (int q = qlo; q < qhi; ++q) {
            const float e = __expf(sSt[k * 65 + q] - mx);
            sSt[k * 65 + q] = e;
            sum += e;
        }
        sRed[t] = sum;   // safe: group reads above are wave-lockstep, own entries only
        __syncthreads();
        const float inv = 1.f / (sRed[k * 4 + 0] + sRed[k * 4 + 1] +
                                 sRed[k * 4 + 2] + sRed[k * 4 + 3]);
        for (int q = j * 16; q < j * 16 + 16; ++q) {
            const float p = (q >= k) ? sSt[k * 65 + q] * inv : 0.f;
            sP[q * 72 + k] = (_Float16)p;
        }
    }
    __syncthreads();

    // ---- O = P @ V : wave w does q-rows [w*16,+16) x 128 dims ----
    f32x4 oa[8];
#pragma unroll
    for (int nt = 0; nt < 8; ++nt) oa[nt] = fz;
#pragma unroll
    for (int kk = 0; kk < 64; kk += 32) {
        const f16x8 ap = *(const f16x8*)(sP + (w * 16 + l15) * 72 + kk + q4 * 8);
#pragma unroll
        for (int nt = 0; nt < 8; ++nt) {
            f16x8 bv;
#pragma unroll
            for (int j = 0; j < 8; ++j)
                bv[j] = sV[(kk + q4 * 8 + j) * 134 + nt * 16 + l15];
            oa[nt] = __builtin_amdgcn_mfma_f32_16x16x32_f16(ap, bv, oa[nt], 0, 0, 0);
        }
    }
#pragma unroll
    for (int nt = 0; nt < 8; ++nt)
#pragma unroll
        for (int i = 0; i < 4; ++i)
            Og[(size_t)(w * 16 + q4 * 4 + i) * ld + nt * 16 + l15] =
                (_Float16)(oa[nt][i]);
}

extern "C" void kernel_launch(void* const* d_in, const int* in_sizes, int n_in,
                              void* d_out, int out_size, void* d_ws, size_t ws_size,
                              hipStream_t stream) {
    const float* x     = (const float*)d_in[0]; // [16384,2048] fp32
    const float* W_qkv = (const float*)d_in[1]; // [6144,2048]  fp32
    const float* b_qkv = (const float*)d_in[2]; // [6144]       fp32
    const float* W_out = (const float*)d_in[3]; // [2048,2048]  fp32
    const float* b_out = (const float*)d_in[4]; // [2048]       fp32
    float* out = (float*)d_out;                 // [16384,2048] fp32

    char* ws = (char*)d_ws;
    _Float16* qkv = (_Float16*)ws;                    // [16384,6144] f16
    _Float16* xh  = (_Float16*)(ws + 201326592);      // [16384,2048] f16
    _Float16* wqh = (_Float16*)(ws + 268435456);      // [6144,2048]  f16
    _Float16* woh = wqh;  // W_out reuses slot after GEMM1 consumed W_qkv

    // 0) downcast inputs
    cvt_f32_f16<<<dim3(33554432 / 2048), 256, 0, stream>>>(x, xh, 33554432 / 8);
    cvt_f32_f16<<<dim3(12582912 / 2048), 256, 0, stream>>>(W_qkv, wqh, 12582912 / 8);
    // 1) qkv = x @ W_qkv^T + b_qkv   (f16 out into ws); 64x24 = 1536 blocks
    gemm_bt_bias<_Float16><<<dim3(1536), 512, 0, stream>>>(
        xh, 2048, wqh, b_qkv, qkv, 6144, 2048, 24);
    // 1b) downcast W_out into the dead W_qkv slot
    cvt_f32_f16<<<dim3(4194304 / 2048), 256, 0, stream>>>(W_out, woh, 4194304 / 8);
    // 2) fused attention per (b,h); output overwrites q-region of qkv
    attn_fused<<<dim3(4096), 256, 0, stream>>>(qkv);
    // 3) out = attn_out @ W_out^T + b_out  (fp32 out); 64x8 = 512 blocks
    gemm_bt_bias<float><<<dim3(512), 512, 0, stream>>>(
        qkv, 6144, woh, b_out, out, 2048, 2048, 8);
}

// Round 2
// 799.372 us; speedup vs baseline: 1.1933x; 1.0534x over previous
//
#include <hip/hip_runtime.h>
#include <hip/hip_fp16.h>

typedef _Float16 f16x8 __attribute__((ext_vector_type(8)));
typedef _Float16 f16x4 __attribute__((ext_vector_type(4)));
typedef float f32x4 __attribute__((ext_vector_type(4)));
typedef short s16x8 __attribute__((ext_vector_type(8)));

typedef __attribute__((address_space(1))) void gvoid;
typedef __attribute__((address_space(3))) void lvoid;

#define GLD_LDS16(g, l) __builtin_amdgcn_global_load_lds((gvoid*)(g), (lvoid*)(l), 16, 0, 0)
#define BAR() __builtin_amdgcn_s_barrier()

// ---- fp32 -> fp16 downcast, 8 elems/thread, 16B stores ----
__global__ __launch_bounds__(256) void cvt_f32_f16(
    const float* __restrict__ src, _Float16* __restrict__ dst, int n8)
{
    const int i = blockIdx.x * 256 + threadIdx.x;
    if (i >= n8) return;
    const float4* s = (const float4*)src;
    const float4 a = s[2 * i], b = s[2 * i + 1];
    f16x8 o;
    o[0] = (_Float16)a.x; o[1] = (_Float16)a.y; o[2] = (_Float16)a.z; o[3] = (_Float16)a.w;
    o[4] = (_Float16)b.x; o[5] = (_Float16)b.y; o[6] = (_Float16)b.z; o[7] = (_Float16)b.w;
    *(f16x8*)(dst + (size_t)i * 8) = o;
}

// ============================================================================
// C[M,N] = A[M,K] @ B[N,K]^T + bias[N]; f16 in, fp32 acc, OutT out.
// 256x256 tile, BK=64, 512 threads (8 waves, 2M x 4N), 16x16x32 f16 MFMA.
// 8-phase schedule (m201 template), raw s_barrier, counted vmcnt(2)/K-tile.
// Verified r1: SQ_LDS_BANK_CONFLICT = 0, 1030 TF. Frozen this round.
// ============================================================================
template <typename OutT>
__global__ __launch_bounds__(512, 1) void gemm_bt_bias(
    const _Float16* __restrict__ A, int lda,
    const _Float16* __restrict__ B,        // ldb == K
    const float* __restrict__ bias,
    OutT* __restrict__ C, int ldc,
    int K, int nbx)
{
    __shared__ alignas(16) _Float16 smem[65536];   // 128 KiB

    const int tid = threadIdx.x;
    const int lane = tid & 63, wv = tid >> 6;
    const int nwg = gridDim.x;
    int bid = blockIdx.x;
    if ((nwg & 7) == 0) bid = (bid & 7) * (nwg >> 3) + (bid >> 3);
    const int m0 = (bid / nbx) * 256, n0 = (bid % nbx) * 256;
    const int wm = wv >> 2, wn = wv & 3;            // wave -> 128x64 sub-tile
    const int l15 = lane & 15, q4 = lane >> 4, l7 = lane & 7;
    const int nk = K >> 6;

    // staging sources: slot s = e*512 + tid; row = s>>3, phys chunk = s&7,
    // fetched logical chunk = (s&7) ^ (row&7). e=0: rows 0..63, e=1: 64..127.
    const int rl = tid >> 3;
    const int cl = (tid & 7) ^ (rl & 7);
    const _Float16* gp00 = A + (size_t)(m0 + rl) * lda + cl * 8;
    const _Float16* gp01 = A + (size_t)(m0 + 64 + rl) * lda + cl * 8;
    const _Float16* gp10 = A + (size_t)(m0 + 128 + rl) * lda + cl * 8;
    const _Float16* gp11 = A + (size_t)(m0 + 192 + rl) * lda + cl * 8;
    const _Float16* gp20 = B + (size_t)(n0 + rl) * (size_t)K + cl * 8;
    const _Float16* gp21 = B + (size_t)(n0 + 64 + rl) * (size_t)K + cl * 8;
    const _Float16* gp30 = B + (size_t)(n0 + 128 + rl) * (size_t)K + cl * 8;
    const _Float16* gp31 = B + (size_t)(n0 + 192 + rl) * (size_t)K + cl * 8;

    f32x4 acc[8][4];
#pragma unroll
    for (int i = 0; i < 8; ++i)
#pragma unroll
        for (int j = 0; j < 4; ++j)
            acc[i][j] = (f32x4){0.f, 0.f, 0.f, 0.f};

    f16x8 fa[4][2], fb0[2][2], fb1[2][2];

#define STAGE(J, tile_) do {                                                  \
    const int dd_ = (tile_) & 1;                                              \
    _Float16* lb_ = &smem[dd_ * 32768 + ((J) >> 1) * 16384 +                  \
                          ((J) & 1) * 8192 + wv * 512];                       \
    const size_t ko_ = (size_t)(tile_) * 64;                                  \
    GLD_LDS16(gp##J##0 + ko_, lb_);                                           \
    GLD_LDS16(gp##J##1 + ko_, lb_ + 4096);                                    \
} while (0)

#define RD_A(d_, mq_) do {                                                    \
    const _Float16* ba_ = &smem[(d_) * 32768];                                \
    _Pragma("unroll")                                                         \
    for (int fi = 0; fi < 4; ++fi) {                                          \
        const int r_ = wm * 128 + (mq_) * 64 + fi * 16 + l15;                 \
        fa[fi][0] = *(const f16x8*)(ba_ + r_ * 64 + ((q4 ^ l7) * 8));         \
        fa[fi][1] = *(const f16x8*)(ba_ + r_ * 64 + (((4 + q4) ^ l7) * 8));   \
    }                                                                         \
} while (0)

#define RD_B(d_, nq_, fbv) do {                                               \
    const _Float16* bb_ = &smem[(d_) * 32768 + 16384];                        \
    _Pragma("unroll")                                                         \
    for (int fj = 0; fj < 2; ++fj) {                                          \
        const int r_ = wn * 64 + (nq_) * 32 + fj * 16 + l15;                  \
        fbv[fj][0] = *(const f16x8*)(bb_ + r_ * 64 + ((q4 ^ l7) * 8));        \
        fbv[fj][1] = *(const f16x8*)(bb_ + r_ * 64 + (((4 + q4) ^ l7) * 8));  \
    }                                                                         \
} while (0)

#define MM(mq_, nq_, fbv) do {                                                \
    __builtin_amdgcn_s_setprio(1);                                            \
    _Pragma("unroll")                                                         \
    for (int ks = 0; ks < 2; ++ks)                                            \
    _Pragma("unroll")                                                         \
    for (int fi = 0; fi < 4; ++fi)                                            \
    _Pragma("unroll")                                                         \
    for (int fj = 0; fj < 2; ++fj)                                            \
        acc[(mq_) * 4 + fi][(nq_) * 2 + fj] =                                 \
            __builtin_amdgcn_mfma_f32_16x16x32_f16(                           \
                fa[fi][ks], fbv[fj][ks],                                      \
                acc[(mq_) * 4 + fi][(nq_) * 2 + fj], 0, 0, 0);                \
    __builtin_amdgcn_s_setprio(0);                                            \
} while (0)

#define GTILE(d_, S1, S2, S3, S4, VMN) do {                                   \
    RD_A(d_, 0); RD_B(d_, 0, fb0);                                           \
    S1;                                                                       \
    BAR(); MM(0, 0, fb0); BAR();                                              \
    RD_B(d_, 1, fb1);                                                         \
    S2;                                                                       \
    BAR(); MM(0, 1, fb1); BAR();                                              \
    RD_A(d_, 1);                                                              \
    S3;                                                                       \
    BAR(); MM(1, 1, fb1); BAR();                                              \
    S4;                                                                       \
    BAR(); MM(1, 0, fb0);                                                     \
    asm volatile("s_waitcnt vmcnt(" #VMN ")" ::: "memory");                   \
    BAR();                                                                    \
} while (0)

    STAGE(0, 0); STAGE(1, 0); STAGE(2, 0); STAGE(3, 0);
    if (nk > 1) {
        STAGE(0, 1);
        asm volatile("s_waitcnt vmcnt(2)" ::: "memory");
    } else {
        asm volatile("s_waitcnt vmcnt(0)" ::: "memory");
    }
    BAR();

    for (int kt = 0; kt < nk - 2; ++kt) {
        const int d = kt & 1;
        GTILE(d, STAGE(1, kt + 1), STAGE(2, kt + 1), STAGE(3, kt + 1),
              STAGE(0, kt + 2), 2);
    }
    if (nk >= 2) {
        GTILE((nk - 2) & 1, STAGE(1, nk - 1), STAGE(2, nk - 1),
              STAGE(3, nk - 1), (void)0, 0);
    }
    {   // last tile: no staging, no barriers needed
        const int d = (nk - 1) & 1;
        RD_A(d, 0); RD_B(d, 0, fb0);
        MM(0, 0, fb0);
        RD_B(d, 1, fb1);
        MM(0, 1, fb1);
        RD_A(d, 1);
        MM(1, 1, fb1);
        MM(1, 0, fb0);
    }

#undef GTILE
#undef MM
#undef RD_B
#undef RD_A
#undef STAGE

    // epilogue: 16x16 C/D layout col=lane&15, row=(lane>>4)*4+reg
#pragma unroll
    for (int nj = 0; nj < 4; ++nj) {
        const int col = n0 + wn * 64 + nj * 16 + l15;
        const float bs = bias[col];
#pragma unroll
        for (int mi = 0; mi < 8; ++mi) {
            const int row = m0 + wm * 128 + mi * 16 + q4 * 4;
#pragma unroll
            for (int i = 0; i < 4; ++i)
                C[(size_t)(row + i) * ldc + col] = (OutT)(acc[mi][nj][i] + bs);
        }
    }
}

// ============================================================================
// Fused attention per (b,h), REWRITTEN (r2): swapped-operand S^T = K Q^T so
// the query-axis softmax is fully in-register (per-lane reduce over 4 regs +
// 4x shfl_xor within the 16-lane group). Causal mask in-register. P packed
// f16x4 -> ds_write_b64 (2-way, free). V stored TRANSPOSED at load in a
// chunk-rotated layout (chunk = ((k>>3)+(d>>3))&7; rows 144B = 4 dwords mod
// 32 banks) -> scalar transpose-writes ~2-way, PV B-frags are ds_read_b128.
// LDS ops/wave ~82 (was ~254), syncthreads 3 (was 6), no serial softmax.
// LDS 53248B -> 3 blocks/CU. grid = 4096 blocks x 256 threads.
// ============================================================================
__global__ __launch_bounds__(256, 3) void attn_fused(_Float16* __restrict__ qkv)
{
    constexpr float SCALE = 0.022097086912079608f; // 1/sqrt(2048)
    __shared__ alignas(16) char smem[53248];
    _Float16* sQ  = (_Float16*)smem;             // [64][136]
    _Float16* sK  = (_Float16*)(smem + 17408);   // [64][136]
    _Float16* sVT = (_Float16*)(smem + 34816);   // [128][72] chunk-rotated V^T
    _Float16* sP  = (_Float16*)smem;             // [64][72]  P[q][k], aliases sQ

    const int t = threadIdx.x;
    const int bh = blockIdx.x;
    const int b = bh >> 4, h = bh & 15;
    const int ld = 6144;
    const _Float16* Qg = qkv + (size_t)b * 64 * ld + h * 128;
    const _Float16* Kg = Qg + 2048;
    const _Float16* Vg = Qg + 4096;
    _Float16* Og = qkv + (size_t)b * 64 * ld + h * 128;

    const int lane = t & 63, w = t >> 6;
    const int l15 = lane & 15, q4 = lane >> 4;

    // ---- load: Q,K row-major [64][136]; V transposed chunk-rotated ----
#pragma unroll
    for (int j = 0; j < 4; ++j) {
        const int i = t + j * 256;
        const int r = i >> 4, c = (i & 15) * 8;       // r = k-row, c = d base
        *(s16x8*)(sQ + r * 136 + c) = *(const s16x8*)(Qg + (size_t)r * ld + c);
        *(s16x8*)(sK + r * 136 + c) = *(const s16x8*)(Kg + (size_t)r * ld + c);
        const f16x8 vv = *(const f16x8*)(Vg + (size_t)r * ld + c);
        const int cp = ((r >> 3) + (c >> 3)) & 7;     // rotated chunk position
#pragma unroll
        for (int p = 0; p < 8; ++p)
            sVT[(c + p) * 72 + cp * 8 + (r & 7)] = vv[p];
    }
    __syncthreads();

    // ---- S^T = K Q^T: wave w owns keys [w*16, w*16+16) x all 64 queries ----
    // D[key-row][q-col]: key = w*16 + q4*4 + i, q = nt*16 + l15.
    f32x4 sc[4];
#pragma unroll
    for (int nt = 0; nt < 4; ++nt) sc[nt] = (f32x4){0.f, 0.f, 0.f, 0.f};
#pragma unroll
    for (int kk = 0; kk < 4; ++kk) {
        const f16x8 ak = *(const f16x8*)(sK + (w * 16 + l15) * 136 + kk * 32 + q4 * 8);
#pragma unroll
        for (int nt = 0; nt < 4; ++nt) {
            const f16x8 bq = *(const f16x8*)(sQ + (nt * 16 + l15) * 136 + kk * 32 + q4 * 8);
            sc[nt] = __builtin_amdgcn_mfma_f32_16x16x32_f16(ak, bq, sc[nt], 0, 0, 0);
        }
    }

    // ---- causal mask + scale, in-register ----
    const int key0 = w * 16 + q4 * 4;
#pragma unroll
    for (int nt = 0; nt < 4; ++nt) {
        const int q = nt * 16 + l15;
#pragma unroll
        for (int i = 0; i < 4; ++i)
            sc[nt][i] = (q >= key0 + i) ? sc[nt][i] * SCALE : -3.0e38f;
    }

    // ---- softmax over q per key: 4-reg reduce + shfl_xor over l15 group ----
    float mx[4], sm[4];
#pragma unroll
    for (int i = 0; i < 4; ++i)
        mx[i] = fmaxf(fmaxf(sc[0][i], sc[1][i]), fmaxf(sc[2][i], sc[3][i]));
#pragma unroll
    for (int m = 1; m <= 8; m <<= 1)
#pragma unroll
        for (int i = 0; i < 4; ++i)
            mx[i] = fmaxf(mx[i], __shfl_xor(mx[i], m, 64));
#pragma unroll
    for (int i = 0; i < 4; ++i) sm[i] = 0.f;
#pragma unroll
    for (int nt = 0; nt < 4; ++nt)
#pragma unroll
        for (int i = 0; i < 4; ++i) {
            const float e = __expf(sc[nt][i] - mx[i]);  // masked -> 0
            sc[nt][i] = e;
            sm[i] += e;
        }
#pragma unroll
    for (int m = 1; m <= 8; m <<= 1)
#pragma unroll
        for (int i = 0; i < 4; ++i)
            sm[i] += __shfl_xor(sm[i], m, 64);
    float inv[4];
#pragma unroll
    for (int i = 0; i < 4; ++i) inv[i] = 1.0f / sm[i];

    __syncthreads();   // all waves done reading sQ/sK before sP overwrite

    // ---- P[q][k] f16, packed 4 consecutive k per lane -> ds_write_b64 ----
#pragma unroll
    for (int nt = 0; nt < 4; ++nt) {
        f16x4 pk;
#pragma unroll
        for (int i = 0; i < 4; ++i)
            pk[i] = (_Float16)(sc[nt][i] * inv[i]);
        *(f16x4*)(sP + (nt * 16 + l15) * 72 + w * 16 + q4 * 4) = pk;
    }
    __syncthreads();

    // ---- O = P V: wave w does q-rows [w*16,+16) x 128 dims, all b128 ----
    f32x4 oa[8];
#pragma unroll
    for (int nt = 0; nt < 8; ++nt) oa[nt] = (f32x4){0.f, 0.f, 0.f, 0.f};
#pragma unroll
    for (int ks = 0; ks < 2; ++ks) {
        const int cc = ks * 4 + q4;                   // k-chunk 0..7
        const f16x8 ap = *(const f16x8*)(sP + (w * 16 + l15) * 72 + cc * 8);
#pragma unroll
        for (int nt = 0; nt < 8; ++nt) {
            const int dd = nt * 16 + l15;
            const f16x8 bv = *(const f16x8*)(sVT + dd * 72 + ((cc + (dd >> 3)) & 7) * 8);
            oa[nt] = __builtin_amdgcn_mfma_f32_16x16x32_f16(ap, bv, oa[nt], 0, 0, 0);
        }
    }

    // ---- store O over Q region ----
#pragma unroll
    for (int nt = 0; nt < 8; ++nt)
#pragma unroll
        for (int i = 0; i < 4; ++i)
            Og[(size_t)(w * 16 + q4 * 4 + i) * ld + nt * 16 + l15] =
                (_Float16)(oa[nt][i]);
}

extern "C" void kernel_launch(void* const* d_in, const int* in_sizes, int n_in,
                              void* d_out, int out_size, void* d_ws, size_t ws_size,
                              hipStream_t stream) {
    const float* x     = (const float*)d_in[0]; // [16384,2048] fp32
    const float* W_qkv = (const float*)d_in[1]; // [6144,2048]  fp32
    const float* b_qkv = (const float*)d_in[2]; // [6144]       fp32
    const float* W_out = (const float*)d_in[3]; // [2048,2048]  fp32
    const float* b_out = (const float*)d_in[4]; // [2048]       fp32
    float* out = (float*)d_out;                 // [16384,2048] fp32

    char* ws = (char*)d_ws;
    _Float16* qkv = (_Float16*)ws;                    // [16384,6144] f16
    _Float16* xh  = (_Float16*)(ws + 201326592);      // [16384,2048] f16
    _Float16* wqh = (_Float16*)(ws + 268435456);      // [6144,2048]  f16
    _Float16* woh = wqh;  // W_out reuses slot after GEMM1 consumed W_qkv

    // 0) downcast inputs
    cvt_f32_f16<<<dim3(33554432 / 2048), 256, 0, stream>>>(x, xh, 33554432 / 8);
    cvt_f32_f16<<<dim3(12582912 / 2048), 256, 0, stream>>>(W_qkv, wqh, 12582912 / 8);
    // 1) qkv = x @ W_qkv^T + b_qkv   (f16 out into ws); 64x24 = 1536 blocks
    gemm_bt_bias<_Float16><<<dim3(1536), 512, 0, stream>>>(
        xh, 2048, wqh, b_qkv, qkv, 6144, 2048, 24);
    // 1b) downcast W_out into the dead W_qkv slot
    cvt_f32_f16<<<dim3(4194304 / 2048), 256, 0, stream>>>(W_out, woh, 4194304 / 8);
    // 2) fused attention per (b,h); output overwrites q-region of qkv
    attn_fused<<<dim3(4096), 256, 0, stream>>>(qkv);
    // 3) out = attn_out @ W_out^T + b_out  (fp32 out); 64x8 = 512 blocks
    gemm_bt_bias<float><<<dim3(512), 512, 0, stream>>>(
        qkv, 6144, woh, b_out, out, 2048, 2048, 8);
}